// Round 1
// baseline (431.513 us; speedup 1.0000x reference)
//
#include <hip/hip_runtime.h>

// NonLocalBlock3D collapsed form:
//   S[b] = X Xt (256x256), s[b] = rowsum(X)
//   kv   = phi_w S g_wT + (phi_w s) g_bT + phi_b (g_w s)T + N phi_b g_bT
//   M    = W_w kvT theta_w / N   (256x256, per batch, bf16)
//   c    = W_w kvT theta_b / N + W_b
//   out  = x + M x + c
#define NB 2
#define CC 256
#define CI 128
#define NN 65536
#define KSPLIT 64
#define KCHUNK 1024   // NN / KSPLIT
#define STAGE 64
#define LDA 72        // 64 + 8 pad (bf16 elements), 144B row stride (16B aligned)
#define LDX 264       // 256 + 8 pad

typedef __bf16 bf16x8 __attribute__((ext_vector_type(8)));
typedef float f32x4 __attribute__((ext_vector_type(4)));

__device__ __forceinline__ unsigned short f2bf(float f) {
  unsigned u = __float_as_uint(f);
  u += 0x7fffu + ((u >> 16) & 1u);   // RNE; inputs finite
  return (unsigned short)(u >> 16);
}

// ---------------- Kernel A: S = X X^T (bf16 MFMA, split-K atomics) + rowsums --
__global__ __launch_bounds__(256) void nl3d_syrk(const float* __restrict__ x,
                                                 float* __restrict__ S,
                                                 float* __restrict__ svec) {
  __shared__ unsigned short ldsA[128 * LDA];
  __shared__ unsigned short ldsB[128 * LDA];
  const int tid = threadIdx.x;
  const int lane = tid & 63;
  const int wv = tid >> 6;
  const int wm = wv >> 1, wn = wv & 1;
  const int b = blockIdx.z;
  const int pair = blockIdx.y;                 // 0:(0,0) 1:(0,1) 2:(1,1)
  const int I = (pair == 2) ? 1 : 0;
  const int J = (pair == 0) ? 0 : 1;
  const bool diag = (I == J);
  const int kc0 = blockIdx.x * KCHUNK;

  const float* xb = x + (size_t)b * CC * NN;
  f32x4 acc[4][4];
  const f32x4 zero4 = {0.f, 0.f, 0.f, 0.f};
#pragma unroll
  for (int i = 0; i < 4; ++i)
#pragma unroll
    for (int j = 0; j < 4; ++j) acc[i][j] = zero4;

  float rsum[8];
#pragma unroll
  for (int i = 0; i < 8; ++i) rsum[i] = 0.f;

  const int rA = tid >> 4;   // 0..15
  const int c4 = tid & 15;
  unsigned short* ldsBp = diag ? ldsA : ldsB;

  for (int s = 0; s < KCHUNK / STAGE; ++s) {
    const int kc = kc0 + s * STAGE;
    float4 fa[8], fb[8];
#pragma unroll
    for (int i = 0; i < 8; ++i) {
      int row = i * 16 + rA;
      fa[i] = *(const float4*)(xb + (size_t)(I * 128 + row) * NN + kc + c4 * 4);
    }
    if (!diag) {
#pragma unroll
      for (int i = 0; i < 8; ++i) {
        int row = i * 16 + rA;
        fb[i] = *(const float4*)(xb + (size_t)(J * 128 + row) * NN + kc + c4 * 4);
      }
    }
    __syncthreads();   // previous stage's MFMA reads done
#pragma unroll
    for (int i = 0; i < 8; ++i) {
      int row = i * 16 + rA;
      ushort4 h;
      h.x = f2bf(fa[i].x); h.y = f2bf(fa[i].y); h.z = f2bf(fa[i].z); h.w = f2bf(fa[i].w);
      *(ushort4*)&ldsA[row * LDA + c4 * 4] = h;
      if (diag) rsum[i] += fa[i].x + fa[i].y + fa[i].z + fa[i].w;
    }
    if (!diag) {
#pragma unroll
      for (int i = 0; i < 8; ++i) {
        int row = i * 16 + rA;
        ushort4 h;
        h.x = f2bf(fb[i].x); h.y = f2bf(fb[i].y); h.z = f2bf(fb[i].z); h.w = f2bf(fb[i].w);
        *(ushort4*)&ldsB[row * LDA + c4 * 4] = h;
      }
    }
    __syncthreads();

    const int m = lane & 15;
    const int kg = (lane >> 4) * 8;
#pragma unroll
    for (int kk = 0; kk < 2; ++kk) {
      bf16x8 afr[4], bfr[4];
#pragma unroll
      for (int mt = 0; mt < 4; ++mt)
        afr[mt] = *(const bf16x8*)&ldsA[(wm * 64 + mt * 16 + m) * LDA + kk * 32 + kg];
#pragma unroll
      for (int nt = 0; nt < 4; ++nt)
        bfr[nt] = *(const bf16x8*)&ldsBp[(wn * 64 + nt * 16 + m) * LDA + kk * 32 + kg];
#pragma unroll
      for (int mt = 0; mt < 4; ++mt)
#pragma unroll
        for (int nt = 0; nt < 4; ++nt)
          acc[mt][nt] = __builtin_amdgcn_mfma_f32_16x16x32_bf16(afr[mt], bfr[nt], acc[mt][nt], 0, 0, 0);
    }
  }

  {
    float* Sb = S + (size_t)b * CC * CC;
    const int col = lane & 15;
    const int rquad = (lane >> 4) * 4;
#pragma unroll
    for (int mt = 0; mt < 4; ++mt)
#pragma unroll
      for (int nt = 0; nt < 4; ++nt)
#pragma unroll
        for (int r = 0; r < 4; ++r) {
          int gi = I * 128 + wm * 64 + mt * 16 + rquad + r;
          int gj = J * 128 + wn * 64 + nt * 16 + col;
          float v = acc[mt][nt][r];
          atomicAdd(&Sb[gi * CC + gj], v);
          if (!diag) atomicAdd(&Sb[gj * CC + gi], v);
        }
  }

  if (diag) {   // rowsums: only diagonal blocks own their 128 rows (no double count)
    __syncthreads();
    float* ldsRS = (float*)ldsA;
    if (tid < 128) ldsRS[tid] = 0.f;
    __syncthreads();
#pragma unroll
    for (int i = 0; i < 8; ++i) atomicAdd(&ldsRS[i * 16 + rA], rsum[i]);
    __syncthreads();
    if (tid < 128) atomicAdd(&svec[b * CC + I * 128 + tid], ldsRS[tid]);
  }
}

// ---------------- tiny chain kernels (fp32, all trivially parallel) ----------
__global__ void nl3d_b0(const float* __restrict__ g_w, float* __restrict__ gwT) {
  int t = blockIdx.x * 256 + threadIdx.x;   // 32768
  int j = t >> 8, d = t & 255;
  gwT[d * CI + j] = g_w[t];
}

__global__ void nl3d_b1(const float* __restrict__ phi_w, const float* __restrict__ S,
                        float* __restrict__ P) {
  int b = blockIdx.x >> 7, i = blockIdx.x & 127, d = threadIdx.x;
  const float* Sb = S + (size_t)b * CC * CC;
  float acc = 0.f;
  for (int c = 0; c < CC; ++c) acc += phi_w[i * CC + c] * Sb[c * CC + d];
  P[((size_t)b * CI + i) * CC + d] = acc;
}

__global__ void nl3d_b2(const float* __restrict__ P, const float* __restrict__ gwT,
                        const float* __restrict__ svec, const float* __restrict__ phi_w,
                        const float* __restrict__ phi_b, const float* __restrict__ g_b,
                        float* __restrict__ kv) {
  int b = blockIdx.x >> 7, i = blockIdx.x & 127, j = threadIdx.x;
  const float* Pr = P + ((size_t)b * CI + i) * CC;
  const float* sv = svec + b * CC;
  float u = 0.f;
  for (int c = 0; c < CC; ++c) u += phi_w[i * CC + c] * sv[c];
  float acc = 0.f, v = 0.f;
  for (int d = 0; d < CC; ++d) {
    float gT = gwT[d * CI + j];
    acc += Pr[d] * gT;
    v += sv[d] * gT;
  }
  kv[((size_t)b * CI + i) * CI + j] = acc + u * g_b[j] + phi_b[i] * (v + (float)NN * g_b[j]);
}

__global__ void nl3d_b3(const float* __restrict__ kv, const float* __restrict__ theta_w,
                        const float* __restrict__ theta_b, float* __restrict__ T2,
                        float* __restrict__ tb2) {
  int b = blockIdx.x >> 7, j = blockIdx.x & 127, c = threadIdx.x;
  const float* kvb = kv + (size_t)b * CI * CI;
  float acc = 0.f;
  for (int i = 0; i < CI; ++i) acc += kvb[i * CI + j] * theta_w[i * CC + c];
  T2[((size_t)b * CI + j) * CC + c] = acc;
  if (c == 0) {
    float t = 0.f;
    for (int i = 0; i < CI; ++i) t += kvb[i * CI + j] * theta_b[i];
    tb2[b * CI + j] = t;
  }
}

__global__ void nl3d_b4(const float* __restrict__ T2, const float* __restrict__ tb2,
                        const float* __restrict__ W_w, const float* __restrict__ W_b,
                        unsigned short* __restrict__ Mbf, float* __restrict__ cvec) {
  int b = blockIdx.x >> 8, o = blockIdx.x & 255, c = threadIdx.x;
  const float inv = 1.0f / (float)NN;
  float acc = 0.f;
  for (int j = 0; j < CI; ++j) acc += W_w[o * CI + j] * T2[((size_t)b * CI + j) * CC + c];
  Mbf[((size_t)b * CC + o) * CC + c] = f2bf(acc * inv);
  if (c == 0) {
    float t = 0.f;
    for (int j = 0; j < CI; ++j) t += W_w[o * CI + j] * tb2[b * CI + j];
    cvec[b * CC + o] = t * inv + W_b[o];
  }
}

// ---------------- Kernel C: out = x + M x + c (bf16 MFMA) --------------------
__global__ __launch_bounds__(256) void nl3d_out(const float* __restrict__ x,
                                                const unsigned short* __restrict__ Mbf,
                                                const float* __restrict__ cvec,
                                                float* __restrict__ out) {
  __shared__ unsigned short xT[64 * LDX];   // [col 0..63][k 0..255] bf16, transposed
  const int tid = threadIdx.x;
  const int lane = tid & 63;
  const int wv = tid >> 6;                  // out-channel group
  const int b = blockIdx.y;
  const int n0 = blockIdx.x * 64;

  const float* xb = x + (size_t)b * CC * NN;
  float* ob = out + (size_t)b * CC * NN;

  {   // stage x[0:256][n0:n0+64] -> transposed bf16 LDS; paired-row dword stores
    const int c4 = tid & 15;
#pragma unroll
    for (int i = 0; i < 8; ++i) {
      int p = i * 16 + (tid >> 4);          // k row-pair 0..127
      float4 f0 = *(const float4*)(xb + (size_t)(2 * p) * NN + n0 + c4 * 4);
      float4 f1 = *(const float4*)(xb + (size_t)(2 * p + 1) * NN + n0 + c4 * 4);
      float a0[4] = {f0.x, f0.y, f0.z, f0.w};
      float a1[4] = {f1.x, f1.y, f1.z, f1.w};
#pragma unroll
      for (int j = 0; j < 4; ++j) {
        unsigned pack = (unsigned)f2bf(a0[j]) | ((unsigned)f2bf(a1[j]) << 16);
        *(unsigned*)&xT[(c4 * 4 + j) * LDX + 2 * p] = pack;
      }
    }
  }
  __syncthreads();

  f32x4 acc[4][4];
  const f32x4 zero4 = {0.f, 0.f, 0.f, 0.f};
#pragma unroll
  for (int i = 0; i < 4; ++i)
#pragma unroll
    for (int j = 0; j < 4; ++j) acc[i][j] = zero4;

  const int m = lane & 15;
  const int kg = (lane >> 4) * 8;
  const unsigned short* Mb = Mbf + (size_t)b * CC * CC;
#pragma unroll
  for (int kc = 0; kc < 8; ++kc) {
    bf16x8 afr[4], bfr[4];
#pragma unroll
    for (int mt = 0; mt < 4; ++mt)
      afr[mt] = *(const bf16x8*)(Mb + (size_t)(wv * 64 + mt * 16 + m) * CC + kc * 32 + kg);
#pragma unroll
    for (int nt = 0; nt < 4; ++nt)
      bfr[nt] = *(const bf16x8*)&xT[(nt * 16 + m) * LDX + kc * 32 + kg];
#pragma unroll
    for (int mt = 0; mt < 4; ++mt)
#pragma unroll
      for (int nt = 0; nt < 4; ++nt)
        acc[mt][nt] = __builtin_amdgcn_mfma_f32_16x16x32_bf16(afr[mt], bfr[nt], acc[mt][nt], 0, 0, 0);
  }

  const int col = lane & 15;
  const int rquad = (lane >> 4) * 4;
#pragma unroll
  for (int mt = 0; mt < 4; ++mt)
#pragma unroll
    for (int r = 0; r < 4; ++r) {
      int o = wv * 64 + mt * 16 + rquad + r;
      float cv = cvec[b * CC + o];
      const float* xrow = xb + (size_t)o * NN + n0;
      float* orow = ob + (size_t)o * NN + n0;
#pragma unroll
      for (int nt = 0; nt < 4; ++nt) {
        int n = nt * 16 + col;
        orow[n] = xrow[n] + acc[mt][nt][r] + cv;   // exact fp32 residual
      }
    }
}

extern "C" void kernel_launch(void* const* d_in, const int* in_sizes, int n_in,
                              void* d_out, int out_size, void* d_ws, size_t ws_size,
                              hipStream_t stream) {
  const float* x       = (const float*)d_in[0];
  const float* g_w     = (const float*)d_in[1];
  const float* g_b     = (const float*)d_in[2];
  const float* theta_w = (const float*)d_in[3];
  const float* theta_b = (const float*)d_in[4];
  const float* phi_w   = (const float*)d_in[5];
  const float* phi_b   = (const float*)d_in[6];
  const float* W_w     = (const float*)d_in[7];
  const float* W_b     = (const float*)d_in[8];
  float* out = (float*)d_out;

  char* ws = (char*)d_ws;
  float* S    = (float*)(ws);                         // 2*256*256 f32 = 512 KiB
  float* svec = (float*)(ws + 524288);                // 2*256
  float* P    = (float*)(ws + 526336);                // 2*128*256
  float* gwT  = (float*)(ws + 788480);                // 256*128
  float* kv   = (float*)(ws + 919552);                // 2*128*128
  float* T2   = (float*)(ws + 1050624);               // 2*128*256
  float* tb2  = (float*)(ws + 1312768);               // 2*128
  unsigned short* Mbf = (unsigned short*)(ws + 1313792); // 2*256*256 bf16
  float* cvec = (float*)(ws + 1575936);               // 2*256

  hipMemsetAsync(ws, 0, 526336, stream);              // zero S + svec (atomic accum)
  nl3d_syrk<<<dim3(KSPLIT, 3, NB), 256, 0, stream>>>(x, S, svec);
  nl3d_b0<<<128, 256, 0, stream>>>(g_w, gwT);
  nl3d_b1<<<NB * CI, 256, 0, stream>>>(phi_w, S, P);
  nl3d_b2<<<NB * CI, 128, 0, stream>>>(P, gwT, svec, phi_w, phi_b, g_b, kv);
  nl3d_b3<<<NB * CI, 256, 0, stream>>>(kv, theta_w, theta_b, T2, tb2);
  nl3d_b4<<<NB * CC, 256, 0, stream>>>(T2, tb2, W_w, W_b, Mbf, cvec);
  nl3d_out<<<dim3(NN / 64, NB), 256, 0, stream>>>(x, Mbf, cvec, out);
}

// Round 2
// 394.365 us; speedup vs baseline: 1.0942x; 1.0942x over previous
//
#include <hip/hip_runtime.h>

// NonLocalBlock3D collapsed form:
//   S[b] = X Xt (256x256), s[b] = rowsum(X)
//   kv   = phi_w S g_wT + (phi_w s) g_bT + phi_b (g_w s)T + N phi_b g_bT
//   M    = W_w kvT theta_w / N   (256x256, per batch, bf16)
//   c    = W_w kvT theta_b / N + W_b
//   out  = x + M x + c
#define NB 2
#define CC 256
#define CI 128
#define NN 65536
#define LDA 72        // 64 + 8 pad (bf16), 144B row stride
#define LDX 264       // 256 + 8 pad (bf16) for out-kernel transposed tile

typedef __bf16 bf16x8 __attribute__((ext_vector_type(8)));
typedef float f32x4 __attribute__((ext_vector_type(4)));

__device__ __forceinline__ unsigned short f2bf(float f) {
  unsigned u = __float_as_uint(f);
  u += 0x7fffu + ((u >> 16) & 1u);   // RNE; inputs finite
  return (unsigned short)(u >> 16);
}

// ---------------- Kernel A: full-tile SYRK, split-K partials (no atomics) ----
// Each block: stages X[0:256][64-chunk] once into LDS (bf16), computes the full
// 256x256 tile with 8 waves (each 64x128), streams fp32 partial to ws.
// use_partial==0 fallback: atomicAdd into S (needs S pre-zeroed).
__global__ __launch_bounds__(512) void nl3d_syrk2(const float* __restrict__ x,
                                                  float* __restrict__ S,
                                                  float* __restrict__ partials,
                                                  float* __restrict__ svec,
                                                  int kchunk, int use_partial) {
  __shared__ unsigned short lds[256 * LDA];   // 36 KB
  const int tid = threadIdx.x;
  const int lane = tid & 63;
  const int wv = tid >> 6;                    // 0..7
  const int wm = wv & 3, wn = wv >> 2;        // 4x2 wave grid: 64 x 128 per wave
  const int b = blockIdx.y;
  const int kc0 = blockIdx.x * kchunk;

  const float* xb = x + (size_t)b * CC * NN;
  f32x4 acc[4][8];
  const f32x4 zero4 = {0.f, 0.f, 0.f, 0.f};
#pragma unroll
  for (int i = 0; i < 4; ++i)
#pragma unroll
    for (int j = 0; j < 8; ++j) acc[i][j] = zero4;

  float rsum[8];
#pragma unroll
  for (int i = 0; i < 8; ++i) rsum[i] = 0.f;

  const int r0 = tid >> 4;    // 0..31
  const int c4 = tid & 15;

  const int stages = kchunk >> 6;
  for (int s = 0; s < stages; ++s) {
    const int kc = kc0 + s * 64;
    float4 f[8];
#pragma unroll
    for (int i = 0; i < 8; ++i) {
      int row = r0 + 32 * i;
      f[i] = *(const float4*)(xb + (size_t)row * NN + kc + c4 * 4);
    }
    __syncthreads();   // prior stage's MFMA LDS reads done
#pragma unroll
    for (int i = 0; i < 8; ++i) {
      int row = r0 + 32 * i;
      ushort4 h;
      h.x = f2bf(f[i].x); h.y = f2bf(f[i].y); h.z = f2bf(f[i].z); h.w = f2bf(f[i].w);
      *(ushort4*)&lds[row * LDA + c4 * 4] = h;
      rsum[i] += f[i].x + f[i].y + f[i].z + f[i].w;
    }
    __syncthreads();

    const int m = lane & 15;
    const int kg = (lane >> 4) * 8;
#pragma unroll
    for (int kk = 0; kk < 2; ++kk) {
      bf16x8 afr[4], bfr[8];
#pragma unroll
      for (int mt = 0; mt < 4; ++mt)
        afr[mt] = *(const bf16x8*)&lds[(wm * 64 + mt * 16 + m) * LDA + kk * 32 + kg];
#pragma unroll
      for (int nt = 0; nt < 8; ++nt)
        bfr[nt] = *(const bf16x8*)&lds[(wn * 128 + nt * 16 + m) * LDA + kk * 32 + kg];
#pragma unroll
      for (int mt = 0; mt < 4; ++mt)
#pragma unroll
        for (int nt = 0; nt < 8; ++nt)
          acc[mt][nt] = __builtin_amdgcn_mfma_f32_16x16x32_bf16(afr[mt], bfr[nt], acc[mt][nt], 0, 0, 0);
    }
  }

  const int col = lane & 15;
  const int rq = (lane >> 4) * 4;
  if (use_partial) {
    float* dst = partials + ((size_t)(b * gridDim.x + blockIdx.x)) * (CC * CC);
#pragma unroll
    for (int mt = 0; mt < 4; ++mt)
#pragma unroll
      for (int nt = 0; nt < 8; ++nt)
#pragma unroll
        for (int r = 0; r < 4; ++r) {
          int gi = wm * 64 + mt * 16 + rq + r;
          int gj = wn * 128 + nt * 16 + col;
          dst[gi * CC + gj] = acc[mt][nt][r];
        }
  } else {
    float* Sb = S + (size_t)b * CC * CC;
#pragma unroll
    for (int mt = 0; mt < 4; ++mt)
#pragma unroll
      for (int nt = 0; nt < 8; ++nt)
#pragma unroll
        for (int r = 0; r < 4; ++r) {
          int gi = wm * 64 + mt * 16 + rq + r;
          int gj = wn * 128 + nt * 16 + col;
          atomicAdd(&Sb[gi * CC + gj], acc[mt][nt][r]);
        }
  }

  // rowsums -> svec (small atomics; svec pre-zeroed)
  __syncthreads();
  float* ldsRS = (float*)lds;
  if (tid < 256) ldsRS[tid] = 0.f;
  __syncthreads();
#pragma unroll
  for (int i = 0; i < 8; ++i) atomicAdd(&ldsRS[r0 + 32 * i], rsum[i]);
  __syncthreads();
  if (tid < 256) atomicAdd(&svec[b * CC + tid], ldsRS[tid]);
}

// ---------------- partial reduction: S = sum over splits ---------------------
__global__ __launch_bounds__(256) void nl3d_reduce(const float* __restrict__ partials,
                                                   float* __restrict__ S, int splits) {
  const int e = blockIdx.x * 256 + threadIdx.x;       // float4 index, 32768 total
  const int b = e >> 14;                              // 16384 float4 per batch
  const int off = e & 16383;
  const float4* p = (const float4*)partials;
  float4 a0 = {0, 0, 0, 0}, a1 = {0, 0, 0, 0};
  const size_t base = (size_t)b * splits * 16384 + off;
  for (int s = 0; s < splits; s += 2) {
    float4 v0 = p[base + (size_t)s * 16384];
    float4 v1 = p[base + (size_t)(s + 1) * 16384];
    a0.x += v0.x; a0.y += v0.y; a0.z += v0.z; a0.w += v0.w;
    a1.x += v1.x; a1.y += v1.y; a1.z += v1.z; a1.w += v1.w;
  }
  float4 r;
  r.x = a0.x + a1.x; r.y = a0.y + a1.y; r.z = a0.z + a1.z; r.w = a0.w + a1.w;
  ((float4*)S)[e] = r;
}

// ---------------- tiny chain kernels (fp32) ----------------------------------
__global__ void nl3d_b0(const float* __restrict__ g_w, float* __restrict__ gwT) {
  int t = blockIdx.x * 256 + threadIdx.x;   // 32768
  int j = t >> 8, d = t & 255;
  gwT[d * CI + j] = g_w[t];
}

__global__ void nl3d_b1(const float* __restrict__ phi_w, const float* __restrict__ S,
                        float* __restrict__ P) {
  int b = blockIdx.x >> 7, i = blockIdx.x & 127, d = threadIdx.x;
  const float* Sb = S + (size_t)b * CC * CC;
  const float* ph = phi_w + i * CC;
  float a0 = 0.f, a1 = 0.f, a2 = 0.f, a3 = 0.f;
  for (int c = 0; c < CC; c += 4) {
    a0 += ph[c + 0] * Sb[(c + 0) * CC + d];
    a1 += ph[c + 1] * Sb[(c + 1) * CC + d];
    a2 += ph[c + 2] * Sb[(c + 2) * CC + d];
    a3 += ph[c + 3] * Sb[(c + 3) * CC + d];
  }
  P[((size_t)b * CI + i) * CC + d] = (a0 + a1) + (a2 + a3);
}

__global__ void nl3d_b2(const float* __restrict__ P, const float* __restrict__ gwT,
                        const float* __restrict__ svec, const float* __restrict__ phi_w,
                        const float* __restrict__ phi_b, const float* __restrict__ g_b,
                        float* __restrict__ kv) {
  int b = blockIdx.x >> 7, i = blockIdx.x & 127, j = threadIdx.x;
  const float* Pr = P + ((size_t)b * CI + i) * CC;
  const float* sv = svec + b * CC;
  const float* ph = phi_w + i * CC;
  float u0 = 0.f, u1 = 0.f;
  for (int c = 0; c < CC; c += 2) {
    u0 += ph[c] * sv[c];
    u1 += ph[c + 1] * sv[c + 1];
  }
  float a0 = 0.f, a1 = 0.f, v0 = 0.f, v1 = 0.f;
  for (int d = 0; d < CC; d += 2) {
    float gT0 = gwT[d * CI + j], gT1 = gwT[(d + 1) * CI + j];
    a0 += Pr[d] * gT0; a1 += Pr[d + 1] * gT1;
    v0 += sv[d] * gT0; v1 += sv[d + 1] * gT1;
  }
  kv[((size_t)b * CI + i) * CI + j] =
      (a0 + a1) + (u0 + u1) * g_b[j] + phi_b[i] * ((v0 + v1) + (float)NN * g_b[j]);
}

__global__ void nl3d_b3(const float* __restrict__ kv, const float* __restrict__ theta_w,
                        const float* __restrict__ theta_b, float* __restrict__ T2,
                        float* __restrict__ tb2) {
  int b = blockIdx.x >> 7, j = blockIdx.x & 127, c = threadIdx.x;
  const float* kvb = kv + (size_t)b * CI * CI;
  float a0 = 0.f, a1 = 0.f;
  for (int i = 0; i < CI; i += 2) {
    a0 += kvb[i * CI + j] * theta_w[i * CC + c];
    a1 += kvb[(i + 1) * CI + j] * theta_w[(i + 1) * CC + c];
  }
  T2[((size_t)b * CI + j) * CC + c] = a0 + a1;
  if (c == 0) {
    float t = 0.f;
    for (int i = 0; i < CI; ++i) t += kvb[i * CI + j] * theta_b[i];
    tb2[b * CI + j] = t;
  }
}

__global__ void nl3d_b4(const float* __restrict__ T2, const float* __restrict__ tb2,
                        const float* __restrict__ W_w, const float* __restrict__ W_b,
                        unsigned short* __restrict__ Mbf, float* __restrict__ cvec) {
  int b = blockIdx.x >> 8, o = blockIdx.x & 255, c = threadIdx.x;
  const float inv = 1.0f / (float)NN;
  const float* Wr = W_w + o * CI;
  float a0 = 0.f, a1 = 0.f;
  for (int j = 0; j < CI; j += 2) {
    a0 += Wr[j] * T2[((size_t)b * CI + j) * CC + c];
    a1 += Wr[j + 1] * T2[((size_t)b * CI + j + 1) * CC + c];
  }
  Mbf[((size_t)b * CC + o) * CC + c] = f2bf((a0 + a1) * inv);
  if (c == 0) {
    float t = 0.f;
    for (int j = 0; j < CI; ++j) t += Wr[j] * tb2[b * CI + j];
    cvec[b * CC + o] = t * inv + W_b[o];
  }
}

// ---------------- Kernel C: out = x + M x + c (bf16 MFMA) --------------------
// xT staging uses an XOR swizzle on the dword index (bits 2-4 keyed by row>>2)
// to break the 8-way LDS bank conflict of the transposed stores.
__global__ __launch_bounds__(256) void nl3d_out(const float* __restrict__ x,
                                                const unsigned short* __restrict__ Mbf,
                                                const float* __restrict__ cvec,
                                                float* __restrict__ out) {
  __shared__ unsigned short xT[64 * LDX];   // [n-col 0..63][k 0..255] bf16, transposed
  const int tid = threadIdx.x;
  const int lane = tid & 63;
  const int wv = tid >> 6;                  // out-channel group
  const int b = blockIdx.y;
  const int n0 = blockIdx.x * 64;

  const float* xb = x + (size_t)b * CC * NN;
  float* ob = out + (size_t)b * CC * NN;

  {   // stage x[0:256][n0:n0+64] -> transposed bf16 LDS (swizzled dword stores)
    const int c4 = tid & 15;
#pragma unroll
    for (int i = 0; i < 8; ++i) {
      int p = i * 16 + (tid >> 4);          // k row-pair 0..127 (= dword index)
      float4 f0 = *(const float4*)(xb + (size_t)(2 * p) * NN + n0 + c4 * 4);
      float4 f1 = *(const float4*)(xb + (size_t)(2 * p + 1) * NN + n0 + c4 * 4);
      float a0[4] = {f0.x, f0.y, f0.z, f0.w};
      float a1[4] = {f1.x, f1.y, f1.z, f1.w};
      int ps = p ^ ((c4 & 7) << 2);         // swizzle: key = (row>>2)&7, row=c4*4+j
#pragma unroll
      for (int j = 0; j < 4; ++j) {
        unsigned pack = (unsigned)f2bf(a0[j]) | ((unsigned)f2bf(a1[j]) << 16);
        *(unsigned*)&xT[(c4 * 4 + j) * LDX + 2 * ps] = pack;
      }
    }
  }
  __syncthreads();

  f32x4 acc[4][4];
  const f32x4 zero4 = {0.f, 0.f, 0.f, 0.f};
#pragma unroll
  for (int i = 0; i < 4; ++i)
#pragma unroll
    for (int j = 0; j < 4; ++j) acc[i][j] = zero4;

  const int m = lane & 15;
  const int kg = (lane >> 4) * 8;
  const unsigned short* Mb = Mbf + (size_t)b * CC * CC;
#pragma unroll
  for (int kc = 0; kc < 8; ++kc) {
    bf16x8 afr[4], bfr[4];
#pragma unroll
    for (int mt = 0; mt < 4; ++mt)
      afr[mt] = *(const bf16x8*)(Mb + (size_t)(wv * 64 + mt * 16 + m) * CC + kc * 32 + kg);
#pragma unroll
    for (int nt = 0; nt < 4; ++nt) {
      int rr = nt * 16 + m;
      int d0 = (kc * 16 + (kg >> 1)) ^ (((rr >> 2) & 7) << 2);
      bfr[nt] = *(const bf16x8*)&xT[rr * LDX + 2 * d0];
    }
#pragma unroll
    for (int mt = 0; mt < 4; ++mt)
#pragma unroll
      for (int nt = 0; nt < 4; ++nt)
        acc[mt][nt] = __builtin_amdgcn_mfma_f32_16x16x32_bf16(afr[mt], bfr[nt], acc[mt][nt], 0, 0, 0);
  }

  const int col = lane & 15;
  const int rquad = (lane >> 4) * 4;
#pragma unroll
  for (int mt = 0; mt < 4; ++mt)
#pragma unroll
    for (int r = 0; r < 4; ++r) {
      int o = wv * 64 + mt * 16 + rquad + r;
      float cv = cvec[b * CC + o];
      const float* xrow = xb + (size_t)o * NN + n0;
      float* orow = ob + (size_t)o * NN + n0;
#pragma unroll
      for (int nt = 0; nt < 4; ++nt) {
        int n = nt * 16 + col;
        orow[n] = xrow[n] + acc[mt][nt][r] + cv;   // exact fp32 residual
      }
    }
}

extern "C" void kernel_launch(void* const* d_in, const int* in_sizes, int n_in,
                              void* d_out, int out_size, void* d_ws, size_t ws_size,
                              hipStream_t stream) {
  const float* x       = (const float*)d_in[0];
  const float* g_w     = (const float*)d_in[1];
  const float* g_b     = (const float*)d_in[2];
  const float* theta_w = (const float*)d_in[3];
  const float* theta_b = (const float*)d_in[4];
  const float* phi_w   = (const float*)d_in[5];
  const float* phi_b   = (const float*)d_in[6];
  const float* W_w     = (const float*)d_in[7];
  const float* W_b     = (const float*)d_in[8];
  float* out = (float*)d_out;

  char* ws = (char*)d_ws;
  float* S    = (float*)(ws);                         // 2*256*256 f32 = 512 KiB
  float* svec = (float*)(ws + 524288);                // 2*256
  float* P    = (float*)(ws + 526336);                // 2*128*256
  float* gwT  = (float*)(ws + 788480);                // 256*128
  float* kv   = (float*)(ws + 919552);                // 2*128*128
  float* T2   = (float*)(ws + 1050624);               // 2*128*256
  float* tb2  = (float*)(ws + 1312768);               // 2*128
  unsigned short* Mbf = (unsigned short*)(ws + 1313792); // 2*256*256 bf16
  float* cvec = (float*)(ws + 1575936);               // 2*256
  float* partials = (float*)(ws + 2097152);           // NB*splits*256KB

  // pick largest power-of-2 split count whose partials fit in ws
  int splits = 0;
  for (int c = 128; c >= 8; c >>= 1) {
    if (2097152 + (size_t)NB * c * CC * CC * 4 <= ws_size) { splits = c; break; }
  }

  if (splits > 0) {
    hipMemsetAsync(svec, 0, 2048, stream);            // svec only (S via reduce)
    nl3d_syrk2<<<dim3(splits, NB), 512, 0, stream>>>(x, S, partials, svec,
                                                     NN / splits, 1);
    nl3d_reduce<<<128, 256, 0, stream>>>(partials, S, splits);
  } else {
    hipMemsetAsync(ws, 0, 526336, stream);            // S + svec (atomic accum)
    nl3d_syrk2<<<dim3(64, NB), 512, 0, stream>>>(x, S, (float*)ws, svec,
                                                 NN / 64, 0);
  }
  nl3d_b0<<<128, 256, 0, stream>>>(g_w, gwT);
  nl3d_b1<<<NB * CI, 256, 0, stream>>>(phi_w, S, P);
  nl3d_b2<<<NB * CI, 128, 0, stream>>>(P, gwT, svec, phi_w, phi_b, g_b, kv);
  nl3d_b3<<<NB * CI, 256, 0, stream>>>(kv, theta_w, theta_b, T2, tb2);
  nl3d_b4<<<NB * CC, 256, 0, stream>>>(T2, tb2, W_w, W_b, Mbf, cvec);
  nl3d_out<<<dim3(NN / 64, NB), 256, 0, stream>>>(x, Mbf, cvec, out);
}